// Round 9
// baseline (384.092 us; speedup 1.0000x reference)
//
#include <hip/hip_runtime.h>

// LIF neuron scan, speculative time-chunked (two-pass), bit-exact.
//
// R7 post-mortem (372 us total: pass1 211, pass2 ~161):
//  - pass2's per-lane match test paid re-sim cost per WAVE: P(64 lanes all
//    match) ~ rate^64 ~ 4% => nearly every chunk re-simulated. THIS ROUND:
//    one neuron per block => match branch is wave-UNIFORM; lanes cooperate
//    (coalesced LDS staging of w, redundant chain, per-lane output columns).
//  - pass1 was memory-stall bound (2.5 TB/s achieved, gather loads, 1-group
//    prefetch). THIS ROUND: 64-step groups (16 float4 in flight) + XCD swizzle
//    co-locating all chunks of a neuron-group for L2 reuse of the 3x-read.
//
// Correctness never depends on speculation: pass2 carries the true running
// state; a chunk is adopted only if the true state matches the recorded entry
// state (bitwise; refr_end in its exact equivalence class: any value <= tmain
// is inert for t >= tmain). Else the chunk is re-simulated with identical
// rounded ops. Numerics = the absmax-0.0-validated step: _rn intrinsics in
// reference order, Markstein 2-FMA correctly-rounded divisions (provably
// RN(a/b) for normal operands), integer refractory end-time.

#define N_NEURONS 4096
#define T_STEPS   8192
#define BN        64                       // threads per block = 1 wave
#define L_CHUNK   256                      // steps per chunk
#define W_WARM    512                      // warmup steps (clamped at t=0)
#define C_CHUNKS  32
#define CN        (C_CHUNKS * N_NEURONS)
#define NXCD      8

struct LifConst {
    float tau_m, v_th, v_rst, r_m, v_rest, a_rst, rcp_tau, rcp_1k;
    int   n_refr;
};

__device__ __forceinline__ float div_rn_fast(float a, float b, float rb) {
    // rb = RN(1/b), b normal; returns RN(a/b) for normal a,b,quotient (Markstein).
    const float q = __fmul_rn(a, rb);
    const float e = __fmaf_rn(-b, q, a);
    return __fmaf_rn(e, rb, q);
}

__device__ __forceinline__ LifConst load_consts(const float* p_tau,
        const float* p_vth, const float* p_vreset, const float* p_rm,
        const float* p_vrest, const float* p_refr) {
    LifConst K;
    K.tau_m = p_tau[0]; K.v_th = p_vth[0]; K.v_rst = p_vreset[0];
    K.r_m = p_rm[0];    K.v_rest = p_vrest[0];
    const float refr_set = __fdiv_rn(p_refr[0], 1.0f);   // refractory / DT
    K.n_refr  = (int)ceilf(refr_set);
    K.rcp_tau = __fdiv_rn(1.0f, K.tau_m);
    K.rcp_1k  = __fdiv_rn(1.0f, 1000.0f);
    K.a_rst   = __fsub_rn(K.v_rest, K.v_rst);
    return K;
}

// one exact LIF step (bit-identical to reference); returns spike
__device__ __forceinline__ bool lif_step(const LifConst& K, float w, int t,
                                         float& v, float& a, int& refr_end) {
    const bool  inr   = t < refr_end;
    const float u     = __fadd_rn(a, w);
    const float dv    = div_rn_fast(u, K.tau_m, K.rcp_tau);
    const float vi    = __fadd_rn(v, dv);
    const bool  cross = vi >= K.v_th;
    const bool  rst   = inr || cross;
    const float a_ch  = __fsub_rn(K.v_rest, vi);
    v = rst ? K.v_rst : vi;
    a = rst ? K.a_rst : a_ch;
    const bool sp = (!inr) && cross;
    refr_end = sp ? (t + 1 + K.n_refr) : refr_end;
    return sp;
}

// ---------------- pass 1: 64-step groups, 16 float4 per buffer ----------------

__device__ __forceinline__ void load_g64(const float4* __restrict__ rowI4,
                                         int tb, float4 buf[16]) {
    #pragma unroll
    for (int j = 0; j < 16; ++j) buf[j] = rowI4[tb / 4 + j];
}

template <bool STORE>
__device__ __forceinline__ void sim_g64(const LifConst& K,
        const float4 buf[16], int tb, float4* __restrict__ rowO4,
        float& v, float& a, int& refr_end, float& prev) {
    #pragma unroll
    for (int j = 0; j < 16; ++j) {
        const float4 x  = buf[j];
        const int    c0 = tb + 4 * j;
        float4 s;
        s.x = prev;                        // col c0 = spike of step c0-1
        #pragma unroll
        for (int k = 0; k < 4; ++k) {
            const int t = c0 + k;
            float spf = 0.0f;
            if (t < T_STEPS - 1) {         // uniform guard (last chunk only)
                const float xi = (k == 0) ? x.x : (k == 1) ? x.y : (k == 2) ? x.z : x.w;
                const float w  = __fmul_rn(K.r_m, div_rn_fast(xi, 1000.0f, K.rcp_1k));
                const bool sp  = lif_step(K, w, t, v, a, refr_end);
                spf = sp ? 1.0f : 0.0f;
            }
            if      (k == 0) s.y = spf;
            else if (k == 1) s.z = spf;
            else if (k == 2) s.w = spf;
            else             prev = spf;
        }
        if (STORE) rowO4[c0 / 4] = s;
    }
}

__global__ __launch_bounds__(BN, 2)
void lif_pass1(const float* __restrict__ I,
               const float* __restrict__ p_tau, const float* __restrict__ p_vth,
               const float* __restrict__ p_vreset, const float* __restrict__ p_rm,
               const float* __restrict__ p_vrest, const float* __restrict__ p_refr,
               float* __restrict__ out, float* __restrict__ ws)
{
    const int lane = threadIdx.x;
    // XCD-aware swizzle: all 32 chunks of a neuron-group land on one XCD
    // (assumes HW round-robins blockIdx % 8 across XCDs; speed-only heuristic)
    const int r  = blockIdx.x % NXCD;              // presumed XCD residue
    const int q  = blockIdx.x / NXCD;              // 0..255
    const int c  = q % C_CHUNKS;                   // chunk id
    const int nb = r * (N_NEURONS / BN / NXCD) + q / C_CHUNKS;  // neuron block
    const int n  = nb * BN + lane;

    const LifConst K = load_consts(p_tau, p_vth, p_vreset, p_rm, p_vrest, p_refr);

    const float4* rowI4 = reinterpret_cast<const float4*>(I   + (size_t)n * T_STEPS);
    float4*       rowO4 = reinterpret_cast<float4*>      (out + (size_t)n * T_STEPS);

    const int tmain  = c * L_CHUNK;
    const int t0     = (tmain >= W_WARM) ? (tmain - W_WARM) : 0;
    const int warm64 = (tmain - t0) / 64;          // 0, 4, or 8 (even)
    const int ngrp64 = warm64 + L_CHUNK / 64;      // +4 main groups

    float v, a, prev;
    int   refr_end;
    if (c == 0) {   // exact start
        v = K.v_rest; a = __fsub_rn(K.v_rest, K.v_rest); refr_end = 0; prev = 0.0f;
    } else {        // canonical guess; warmup contracts to the true trajectory
        v = K.v_rst;  a = K.a_rst;  refr_end = t0;  prev = 0.0f;
    }

    float* vS = ws + 0 * CN;  float* pS = ws + 1 * CN;
    int*   rS = (int*)(ws + 2 * CN);
    float* vE = ws + 3 * CN;  float* pE = ws + 4 * CN;
    int*   rE = (int*)(ws + 5 * CN);
    const int sidx = c * N_NEURONS + n;

    float4 bufA[16], bufB[16];                     // static indexing only
    load_g64(rowI4, t0, bufA);

    // warmup pairs (no stores)
    for (int p = 0; p < warm64 / 2; ++p) {
        const int gA = 2 * p, gB = 2 * p + 1;
        load_g64(rowI4, t0 + gB * 64, bufB);
        sim_g64<false>(K, bufA, t0 + gA * 64, rowO4, v, a, refr_end, prev);
        load_g64(rowI4, t0 + (gB + 1) * 64, bufA);   // gB+1 <= warm64 < ngrp64
        sim_g64<false>(K, bufB, t0 + gB * 64, rowO4, v, a, refr_end, prev);
    }

    vS[sidx] = v; pS[sidx] = prev; rS[sidx] = refr_end;   // entry state S[c]

    // main pairs (stores on); bufA already holds group warm64
    for (int p = 0; p < 2; ++p) {
        const int gA = warm64 + 2 * p, gB = gA + 1;
        load_g64(rowI4, t0 + gB * 64, bufB);
        sim_g64<true>(K, bufA, t0 + gA * 64, rowO4, v, a, refr_end, prev);
        if (gB + 1 < ngrp64) load_g64(rowI4, t0 + (gB + 1) * 64, bufA);
        sim_g64<true>(K, bufB, t0 + gB * 64, rowO4, v, a, refr_end, prev);
    }

    vE[sidx] = v; pE[sidx] = prev; rE[sidx] = refr_end;   // exit state E[c]
}

// ------------- pass 2: one neuron per block, wave-uniform branching -----------

__global__ __launch_bounds__(BN)
void lif_pass2(const float* __restrict__ I,
               const float* __restrict__ p_tau, const float* __restrict__ p_vth,
               const float* __restrict__ p_vreset, const float* __restrict__ p_rm,
               const float* __restrict__ p_vrest, const float* __restrict__ p_refr,
               float* __restrict__ out, const float* __restrict__ ws)
{
    const int lane = threadIdx.x;
    const int n    = blockIdx.x;                   // one neuron per block

    const LifConst K = load_consts(p_tau, p_vth, p_vreset, p_rm, p_vrest, p_refr);

    const float4* rowI4 = reinterpret_cast<const float4*>(I + (size_t)n * T_STEPS);
    float*        rowO  = out + (size_t)n * T_STEPS;

    const float* vS = ws + 0 * CN;  const float* pS = ws + 1 * CN;
    const int*   rS = (const int*)(ws + 2 * CN);
    const float* vE = ws + 3 * CN;  const float* pE = ws + 4 * CN;
    const int*   rE = (const int*)(ws + 5 * CN);

    __shared__ float wsh[L_CHUNK];                 // staged w for one chunk (1 KB)

    // chunk 0 is exact: true state after it = E[0]
    float v        = vE[n];
    float prev     = pE[n];
    int   refr_end = rE[n];

    for (int c = 1; c < C_CHUNKS; ++c) {
        const int sidx  = c * N_NEURONS + n;
        const int tmain = c * L_CHUNK;

        const float vs = vS[sidx], ps = pS[sidx];  // uniform loads (scalar)
        const int   rs = rS[sidx];

        // refr equivalence: any refr_end <= tmain is inert for all t >= tmain
        const bool refr_ok = (refr_end == rs) ||
                             ((refr_end <= tmain) && (rs <= tmain));
        const bool match   = (v == vs) && (prev == ps) && refr_ok;  // uniform

        if (match) {
            v = vE[sidx]; prev = pE[sidx]; refr_end = rE[sidx];
        } else {
            // ---- cooperative exact re-sim of chunk c from the true state ----
            // stage w = r_m * RN(I/1000) (identical rounding), coalesced
            const float4 xi = rowI4[tmain / 4 + lane];
            float4 wv;
            wv.x = __fmul_rn(K.r_m, div_rn_fast(xi.x, 1000.0f, K.rcp_1k));
            wv.y = __fmul_rn(K.r_m, div_rn_fast(xi.y, 1000.0f, K.rcp_1k));
            wv.z = __fmul_rn(K.r_m, div_rn_fast(xi.z, 1000.0f, K.rcp_1k));
            wv.w = __fmul_rn(K.r_m, div_rn_fast(xi.w, 1000.0f, K.rcp_1k));
            *reinterpret_cast<float4*>(&wsh[4 * lane]) = wv;
            __syncthreads();

            // all lanes redundantly run the chain; lane owns cols {64j + lane}
            float a = __fsub_rn(K.v_rest, v);      // == maintained a, exactly
            float sl0 = (lane == 0) ? prev : 0.0f; // col tmain = prev_in
            float sl1 = 0.0f, sl2 = 0.0f, sl3 = 0.0f;

            // section JJ covers local steps 64*JJ .. 64*JJ+63; LDS broadcast
            // reads prefetched 8 steps (2 float4) ahead of the chain.
            #define P2_SECTION(JJ, SLCUR, SEAM_STMT)                           \
            {                                                                  \
                float4 a0 = *reinterpret_cast<const float4*>(&wsh[64 * JJ]);   \
                float4 a1 = *reinterpret_cast<const float4*>(&wsh[64 * JJ + 4]);\
                for (int j2 = 0; j2 < 8; ++j2) {                               \
                    float4 b0, b1;                                             \
                    if (j2 < 7) {                                              \
                        b0 = *reinterpret_cast<const float4*>(&wsh[64*JJ + 8*j2 + 8]); \
                        b1 = *reinterpret_cast<const float4*>(&wsh[64*JJ + 8*j2 + 12]);\
                    }                                                          \
                    _Pragma("unroll")                                          \
                    for (int m = 0; m < 8; ++m) {                              \
                        const int t = tmain + 64 * JJ + 8 * j2 + m;            \
                        float spf = 0.0f;                                      \
                        if (t < T_STEPS - 1) {                                 \
                            const float w = (m == 0) ? a0.x : (m == 1) ? a0.y  \
                                          : (m == 2) ? a0.z : (m == 3) ? a0.w  \
                                          : (m == 4) ? a1.x : (m == 5) ? a1.y  \
                                          : (m == 6) ? a1.z : a1.w;            \
                            const bool sp = lif_step(K, w, t, v, a, refr_end); \
                            spf = sp ? 1.0f : 0.0f;                            \
                        }                                                      \
                        prev  = spf;                                           \
                        SLCUR = (lane == 8 * j2 + m + 1) ? spf : SLCUR;        \
                        if (m == 7) { SEAM_STMT }                              \
                    }                                                          \
                    if (j2 < 7) { a0 = b0; a1 = b1; }                          \
                }                                                              \
            }

            P2_SECTION(0, sl0, sl1 = (j2 == 7 && lane == 0) ? spf : sl1;)
            P2_SECTION(1, sl1, sl2 = (j2 == 7 && lane == 0) ? spf : sl2;)
            P2_SECTION(2, sl2, sl3 = (j2 == 7 && lane == 0) ? spf : sl3;)
            P2_SECTION(3, sl3, )
            #undef P2_SECTION

            // coalesced patch of the chunk's 256 output columns
            rowO[tmain +       lane] = sl0;
            rowO[tmain +  64 + lane] = sl1;
            rowO[tmain + 128 + lane] = sl2;
            rowO[tmain + 192 + lane] = sl3;
            __syncthreads();    // wsh reuse guard for next mismatched chunk
        }
    }
}

extern "C" void kernel_launch(void* const* d_in, const int* in_sizes, int n_in,
                              void* d_out, int out_size, void* d_ws, size_t ws_size,
                              hipStream_t stream)
{
    const float* I = (const float*)d_in[0];
    float* out = (float*)d_out;
    float* ws  = (float*)d_ws;    // 6 * 32 * 4096 * 4 B = 3 MiB

    lif_pass1<<<dim3((N_NEURONS / BN) * C_CHUNKS), dim3(BN), 0, stream>>>(
        I, (const float*)d_in[1], (const float*)d_in[2], (const float*)d_in[3],
        (const float*)d_in[4], (const float*)d_in[5], (const float*)d_in[6],
        out, ws);

    lif_pass2<<<dim3(N_NEURONS), dim3(BN), 0, stream>>>(
        I, (const float*)d_in[1], (const float*)d_in[2], (const float*)d_in[3],
        (const float*)d_in[4], (const float*)d_in[5], (const float*)d_in[6],
        out, ws);
}